// Round 14
// baseline (1216.170 us; speedup 1.0000x reference)
//
#include <hip/hip_runtime.h>
#include <math.h>
#include <float.h>

// VQ-VAE VectorQuantizer forward, MI355X (gfx950). R14.
//   x: [16,4096,256] f32 (N=65536 rows), embedding: [4096,256] f32 (K=4096).
//   out: [0,16777216) quantized_st | [Q_OFF,+65536) indices(float) | [L_OFF] loss
//
// R13 post-mortem: counted-vmcnt pipeline didn't engage (965us, MfmaUtil 7.3%,
// FETCH doubled). R14 = SPLIT-PHASE for attribution + known-overhead removal:
//  - k_filter: A-tile (128 rows x 256 d bf16 = 64 KB) loaded ONCE into LDS;
//    per round only B staged (1 global_load_lds/thread), 4-deep buffers,
//    counted vmcnt(3). 512-thread block (8 waves), 1 block/CU, 98 KB LDS.
//    Writes candidate list + count to global scratch.
//  - k_rescore: separate dispatch; per filter-block exact fp32 rescore into
//    LDS best, writes indices directly.
//  The profile now attributes filter vs rescore time directly.
//
// Exactness (R1/R5/R6/R10/R12-proven): reference score bits =
// fl(xnorm - 2*serial_dot); AVX2-tree xnorm; ties -> lowest index via packed
// (key|idx) u64 atomicMin (block-local rows). Filter in dot space: collect
// d~ >= mu - Wd with running max mu <= true max (superset, order-independent);
// Wd = 0.018*||x||_blk*eM + 5e-5 >= 2E, E <= 2^-7*||x||*eM; exact fp32
// rescore decides. 16x16x32 A/B/C fragment maps HW-validated.
//
// Scratch inside out[0..16.7M) (overwritten by k_output at the end):
//   xb bf16 @0 | ebp bf16 @EB_OFF | xnorm @XN_OFF | emax2 @EMAX_OFF
//   cnts u32 @CNTS_OFF (512) | glist u32 @LIST_OFF (512 x 12288)

typedef unsigned int u32; typedef unsigned long long u64; typedef unsigned short u16;
typedef __attribute__((ext_vector_type(8))) short bf16x8;
typedef __attribute__((ext_vector_type(4))) float f32x4;

#define DIM      256
#define Q_OFF    16777216
#define L_OFF    16842752
#define EB_OFF   8388608
#define XN_OFF   8912896
#define EMAX_OFF 8978432
#define CNTS_OFF 8978440
#define LIST_OFF 9109520
#define CAP8     12288

__device__ __forceinline__ u16 f2bf(float f) {           // RNE f32->bf16
    u32 u = __float_as_uint(f);
    return (u16)((u + 0x7FFFu + ((u >> 16) & 1u)) >> 16);
}
__device__ __forceinline__ u32 fkey(float f) {           // monotone f32->u32
    u32 u = __float_as_uint(f);
    return (u & 0x80000000u) ? ~u : (u | 0x80000000u);
}

// exact serial fmaf dot (R1-proven order) + packed atomicMin into LDS best
__device__ __forceinline__ void rescoreL(int lrow, int code,
                                         const float* __restrict__ xblk,
                                         const float* __restrict__ emb,
                                         const float* __restrict__ xnblk,
                                         u64* __restrict__ bestL) {
    const float4* xr = (const float4*)(xblk + (u32)lrow * DIM);
    const float4* er = (const float4*)(emb + (u32)code * DIM);
    float acc = 0.f;
    #pragma unroll 8
    for (int q = 0; q < 64; ++q) {
        float4 a = xr[q], b = er[q];
        acc = fmaf(a.x, b.x, acc); acc = fmaf(a.y, b.y, acc);
        acc = fmaf(a.z, b.z, acc); acc = fmaf(a.w, b.w, acc);
    }
    float sc = fmaf(-2.f, acc, xnblk[lrow]);
    atomicMin(&bestL[lrow], ((u64)fkey(sc) << 32) | (u32)code);
}

// ---------------------------------------------------------------------------
__global__ void k_init(float* __restrict__ out) {
    out[EMAX_OFF] = 0.f; out[L_OFF] = 0.f;
}

__global__ void k_conv(const float* __restrict__ x, u16* __restrict__ xb) {
    int g = blockIdx.x * 256 + threadIdx.x;              // 2,097,152 x 8 floats
    const float4* p = (const float4*)x + g * 2;
    float4 a = p[0], b = p[1];
    uint4 o;
    o.x = (u32)f2bf(a.x) | ((u32)f2bf(a.y) << 16);
    o.y = (u32)f2bf(a.z) | ((u32)f2bf(a.w) << 16);
    o.z = (u32)f2bf(b.x) | ((u32)f2bf(b.y) << 16);
    o.w = (u32)f2bf(b.z) | ((u32)f2bf(b.w) << 16);
    ((uint4*)xb)[g] = o;
}

// pack ebp[G][code][8] (G=k>>3) + per-code norm^2 -> atomicMax emax2
__global__ void k_packe(const float* __restrict__ e, u16* __restrict__ ebp,
                        float* __restrict__ out) {
    int tid = blockIdx.x * 256 + threadIdx.x;            // 131,072
    int c = tid >> 5, G = tid & 31;
    const float4* p = (const float4*)(e + c * DIM + G * 8);
    float4 a = p[0], b = p[1];
    uint4 o;
    o.x = (u32)f2bf(a.x) | ((u32)f2bf(a.y) << 16);
    o.y = (u32)f2bf(a.z) | ((u32)f2bf(a.w) << 16);
    o.z = (u32)f2bf(b.x) | ((u32)f2bf(b.y) << 16);
    o.w = (u32)f2bf(b.z) | ((u32)f2bf(b.w) << 16);
    *(uint4*)(ebp + (u32)(G * 4096 + c) * 8u) = o;
    float s8 = a.x*a.x + a.y*a.y + a.z*a.z + a.w*a.w
             + b.x*b.x + b.y*b.y + b.z*b.z + b.w*b.w;
    #pragma unroll
    for (int off = 1; off < 32; off <<= 1) s8 += __shfl_xor(s8, off, 64);
    if ((threadIdx.x & 31) == 0)
        atomicMax((int*)(out + EMAX_OFF), __float_as_int(s8));
}

// AVX2-tree row norm, 8 lanes/row (bit-identical to R1)
__global__ void k_prep(const float* __restrict__ x, float* __restrict__ out) {
    int g = blockIdx.x * 256 + threadIdx.x;              // 524,288
    int row = g >> 3, l = g & 7;
    const float* xr = x + row * DIM;
    float p = 0.f;
    #pragma unroll
    for (int i = 0; i < 32; ++i) { float v = xr[i*8 + l]; p = fmaf(v, v, p); }
    float q = p + __shfl_down(p, 4, 64);
    float r = q + __shfl_down(q, 2, 64);
    float s = r + __shfl_down(r, 1, 64);
    if (l == 0) out[XN_OFF + row] = s;
}

// ---------------------------------------------------------------------------
// k_filter: 512 blocks x 512 thr (8 waves, 2x4 wave grid; wave = 64 rows x
// 32 codes). Block = 128 rows x all 4096 codes. A image (64 frags of 1 KB,
// fragment-ordered [KC][mf]) loaded ONCE via global_load_lds. Per round
// (CT=m>>3, KC=m&7): stage 8 B-frags (1/thread), 4-deep buffers, vmcnt(3).
// Per wave: 4 A-reads + 2 B-reads (LDS, conflict-free) -> 8 MFMA.
// Seed 16 rounds (CT 0..1) -> converged md; main 256 rounds collect.
// ---------------------------------------------------------------------------
__launch_bounds__(512, 1)
__global__ void k_filter(const u16* __restrict__ xb, const u16* __restrict__ ebp,
                         const float* __restrict__ xnorm, const float* __restrict__ emax2,
                         u32* __restrict__ glist, u32* __restrict__ cnts) {
    __shared__ u16 Aimg[64 * 512];         // 64 KB, loaded once
    __shared__ u16 Bimg[4][4096];          // 4 x 8 KB
    __shared__ u32 cnt, ovf;
    __shared__ int xmax_bits;

    const int t = threadIdx.x, w = t >> 6, l = t & 63;
    const int l16 = l & 15, lhi = l >> 4;
    const int wr = w >> 2, wc = w & 3;
    const int brow = blockIdx.x * 128;
    u32* mylist = glist + (u32)blockIdx.x * CAP8;
    if (t == 0) { cnt = 0u; ovf = 0u; xmax_bits = 0; }
    __syncthreads();
    if (t < 128) atomicMax(&xmax_bits, __float_as_int(xnorm[brow + t]));

    // ---- A image: frag F = KC*8+mf (KC 0..7, mf 0..7), 1 KB each, once ----
    #pragma unroll
    for (int it = 0; it < 8; ++it) {
        const int F = it*8 + w;
        const int KC = F >> 3, mf = F & 7;
        const u16* ga = xb + (u32)(brow + mf*16 + l16) * 256u
                           + (u32)(KC*32 + lhi*8);
        __builtin_amdgcn_global_load_lds(
            (const __attribute__((address_space(1))) u32*)ga,
            (__attribute__((address_space(3))) u32*)&Aimg[F*512], 16, 0, 0);
    }
    __syncthreads();
    const float Wd = 0.018f * sqrtf(__int_as_float(xmax_bits)) * sqrtf(emax2[0])
                   + 5.0e-5f;

    float md[16];
    #pragma unroll
    for (int s = 0; s < 16; ++s) md[s] = -FLT_MAX;
    f32x4 acc[4][2] = {};

    // ---- stage B tile (CT,KC) into buffer B: 8 frags, wave w stages frag w.
    // frag w: codes CT*128 + w*16 + l16, G-plane KC*4 + lhi. 1 gload/thread.
    #define STAGE_B(B, CT, KC) { \
        const u16* gb_ = ebp + ((u32)((KC)*4 + lhi) * 4096u \
                               + (u32)((CT)*128 + w*16 + l16)) * 8u; \
        __builtin_amdgcn_global_load_lds( \
            (const __attribute__((address_space(1))) u32*)gb_, \
            (__attribute__((address_space(3))) u32*)&Bimg[B][w*512], 16, 0, 0); }

    // ---- one round's compute: 4 A-frags (KC, wr*4+i) + 2 B-frags -> 8 MFMA
    #define CHUNK_MFMA(B, KC) { \
        bf16x8 a_[4], b_[2]; \
        _Pragma("unroll") \
        for (int i_ = 0; i_ < 4; ++i_) \
            a_[i_] = *(const bf16x8*)&Aimg[((KC)*8 + wr*4 + i_)*512 + l*8]; \
        _Pragma("unroll") \
        for (int j_ = 0; j_ < 2; ++j_) \
            b_[j_] = *(const bf16x8*)&Bimg[B][(wc*2 + j_)*512 + l*8]; \
        __builtin_amdgcn_s_setprio(1); \
        _Pragma("unroll") \
        for (int i_ = 0; i_ < 4; ++i_) \
            _Pragma("unroll") \
            for (int j_ = 0; j_ < 2; ++j_) \
                acc[i_][j_] = __builtin_amdgcn_mfma_f32_16x16x32_bf16( \
                    a_[i_], b_[j_], acc[i_][j_], 0, 0, 0); \
        __builtin_amdgcn_s_setprio(0); \
    }

    #define MD_RESYNC { \
        _Pragma("unroll") \
        for (int s_ = 0; s_ < 16; ++s_) { \
            float v_ = md[s_]; \
            _Pragma("unroll") \
            for (int off_ = 1; off_ < 16; off_ <<= 1) \
                v_ = fmaxf(v_, __shfl_xor(v_, off_, 64)); \
            md[s_] = v_; \
        } }

    // 4-deep pipeline head: stage tile m+3, wait own tile m (vmcnt counts
    // outstanding: tiles m..m+3 = 4 loads/thread -> vmcnt(3) retires tile m).
    #define PIPE_HEAD(M_TOT) { \
        const int mm = m + 3; \
        if (mm < (M_TOT)) { \
            STAGE_B(mm & 3, mm >> 3, mm & 7) \
            asm volatile("s_waitcnt vmcnt(3)" ::: "memory"); \
        } else if (m + 2 < (M_TOT)) { \
            asm volatile("s_waitcnt vmcnt(2)" ::: "memory"); \
        } else if (m + 1 < (M_TOT)) { \
            asm volatile("s_waitcnt vmcnt(1)" ::: "memory"); \
        } else { \
            asm volatile("s_waitcnt vmcnt(0)" ::: "memory"); \
        } \
        __builtin_amdgcn_s_barrier(); }

    // ================ seed: 16 rounds, CT 0..1 (256 codes), md only ==========
    STAGE_B(0, 0, 0) STAGE_B(1, 0, 1) STAGE_B(2, 0, 2)
    #pragma unroll 1
    for (int m = 0; m < 16; ++m) {
        PIPE_HEAD(16)
        CHUNK_MFMA(m & 3, m & 7)
        if ((m & 7) == 7) {
            #pragma unroll
            for (int i = 0; i < 4; ++i)
                #pragma unroll
                for (int j = 0; j < 2; ++j)
                    #pragma unroll
                    for (int r = 0; r < 4; ++r) {
                        md[i*4+r] = fmaxf(md[i*4+r], acc[i][j][r]);
                        acc[i][j][r] = 0.f;
                    }
        }
        __builtin_amdgcn_s_barrier();
    }
    MD_RESYNC   // md = true row max over 256 seed codes

    // ================ main: 256 rounds (CT=m>>3, KC=m&7) ================
    STAGE_B(0, 0, 0) STAGE_B(1, 0, 1) STAGE_B(2, 0, 2)
    #pragma unroll 1
    for (int m = 0; m < 256; ++m) {
        PIPE_HEAD(256)
        CHUNK_MFMA(m & 3, m & 7)
        if ((m & 7) == 7) {
            const int ct = m >> 3;
            #pragma unroll
            for (int i = 0; i < 4; ++i)
                #pragma unroll
                for (int j = 0; j < 2; ++j)
                    #pragma unroll
                    for (int r = 0; r < 4; ++r) {
                        float v = acc[i][j][r];
                        float mu = fmaxf(md[i*4+r], v);
                        md[i*4+r] = mu;
                        if (v >= mu - Wd) {
                            u32 rl = (u32)(wr*64 + i*16 + lhi*4 + r);
                            u32 code = (u32)(ct*128 + (wc*2 + j)*16 + l16);
                            u32 pos = atomicAdd(&cnt, 1u);
                            if (pos < CAP8) mylist[pos] = (rl << 12) | code;
                            else ovf = 1u;
                        }
                        acc[i][j][r] = 0.f;
                    }
            if ((ct & 3) == 3) MD_RESYNC
        }
        __builtin_amdgcn_s_barrier();
    }

    __syncthreads();
    if (t == 0) cnts[blockIdx.x] = cnt | (ovf << 31);
}

// ---------------------------------------------------------------------------
// k_rescore: 512 blocks x 256 thr; block b rescores filter-block b's list,
// block-local LDS best, writes indices directly.
// ---------------------------------------------------------------------------
__global__ void k_rescore(const float* __restrict__ x, const float* __restrict__ emb,
                          const float* __restrict__ xnorm, const u32* __restrict__ glist,
                          const u32* __restrict__ cnts, float* __restrict__ idxf) {
    __shared__ u64 bestL[128];
    const int t = threadIdx.x, b = blockIdx.x;
    const int brow = b * 128;
    if (t < 128) bestL[t] = ~0ULL;
    __syncthreads();
    const float* xblk = x + (u32)brow * DIM;
    const float* xnblk = xnorm + brow;
    u32 c = cnts[b];
    if (c & 0x80000000u) {                   // ovf safety net
        for (u32 p = (u32)t; p < 524288u; p += 256u)
            rescoreL((int)(p >> 12), (int)(p & 4095u), xblk, emb, xnblk, bestL);
    } else {
        const u32* mylist = glist + (u32)b * CAP8;
        for (u32 i = (u32)t; i < c; i += 256u) {
            u32 e = mylist[i];
            rescoreL((int)(e >> 12), (int)(e & 4095u), xblk, emb, xnblk, bestL);
        }
    }
    __syncthreads();
    if (t < 128) idxf[brow + t] = (float)(u32)(bestL[t] & 0xFFFFFFFFu);
}

// ---------------------------------------------------------------------------
__global__ void k_output(const float* __restrict__ x, const float* __restrict__ emb,
                         const float* __restrict__ idx_f, float* __restrict__ out) {
    const int t = blockIdx.x * 256 + threadIdx.x;
    float lsum = 0.f;
    #pragma unroll
    for (int c = 0; c < 8; ++c) {
        int f4  = c * (2048*256) + t;
        int row = f4 >> 6;
        int c4  = f4 & 63;
        int idx = (int)idx_f[Q_OFF + row];
        float4 q  = ((const float4*)emb)[idx*64 + c4];
        float4 xv = ((const float4*)x)[f4];
        float4 o; float d;
        d = q.x - xv.x; o.x = xv.x + d; lsum = fmaf(d,d,lsum);
        d = q.y - xv.y; o.y = xv.y + d; lsum = fmaf(d,d,lsum);
        d = q.z - xv.z; o.z = xv.z + d; lsum = fmaf(d,d,lsum);
        d = q.w - xv.w; o.w = xv.w + d; lsum = fmaf(d,d,lsum);
        ((float4*)out)[f4] = o;
    }
    #pragma unroll
    for (int off = 32; off > 0; off >>= 1) lsum += __shfl_down(lsum, off, 64);
    __shared__ float wsum[4];
    if ((threadIdx.x & 63) == 0) wsum[threadIdx.x >> 6] = lsum;
    __syncthreads();
    if (threadIdx.x == 0)
        atomicAdd(&out[L_OFF], (wsum[0]+wsum[1]) + (wsum[2]+wsum[3]));
}

__global__ void k_final(float* __restrict__ out) {
    if (threadIdx.x == 0 && blockIdx.x == 0) {
        float m = out[L_OFF] * (1.f/16777216.f);
        out[L_OFF] = m + 0.25f * m;
    }
}

extern "C" void kernel_launch(void* const* d_in, const int* in_sizes, int n_in,
                              void* d_out, int out_size, void* d_ws, size_t ws_size,
                              hipStream_t stream) {
    const float* x   = (const float*)d_in[0];
    const float* emb = (const float*)d_in[1];
    float* out = (float*)d_out;
    u16* xb  = (u16*)out;
    u16* ebp = (u16*)(out + EB_OFF);
    u32* cnts = (u32*)(out + CNTS_OFF);
    u32* glist = (u32*)(out + LIST_OFF);

    hipLaunchKernelGGL(k_init,    dim3(1),    dim3(1),   0, stream, out);
    hipLaunchKernelGGL(k_conv,    dim3(8192), dim3(256), 0, stream, x, xb);
    hipLaunchKernelGGL(k_packe,   dim3(512),  dim3(256), 0, stream, emb, ebp, out);
    hipLaunchKernelGGL(k_prep,    dim3(2048), dim3(256), 0, stream, x, out);
    hipLaunchKernelGGL(k_filter,  dim3(512),  dim3(512), 0, stream,
                       xb, ebp, out + XN_OFF, out + EMAX_OFF, glist, cnts);
    hipLaunchKernelGGL(k_rescore, dim3(512),  dim3(256), 0, stream,
                       x, emb, out + XN_OFF, glist, cnts, out + Q_OFF);
    hipLaunchKernelGGL(k_output,  dim3(2048), dim3(256), 0, stream, x, emb, out, out);
    hipLaunchKernelGGL(k_final,   dim3(1),    dim3(1),   0, stream, out);
}